// Round 5
// baseline (11075.365 us; speedup 1.0000x reference)
//
#include <hip/hip_runtime.h>
#include <hip/hip_fp16.h>
#include <stdint.h>

// LSTM policy rollout, weight-resident, spill-proof geometry.
// 256 blocks x 1024 threads (1 block/CU, 4 waves/SIMD -> 128-VGPR cap).
// Block owns 16 h-rows = 48 gate rows; each of 16 waves owns 3 rows:
//   2 rows in VGPRs (64 regs f16x2) + 1 row in LDS (16 rows = 128 KB).
// Register demand ~100 < 128 cap => no spill.
// Per-step global traffic = h exchange (24 KB) + 256 flag words.

#define HID    4096
#define CTX    1024
#define NSTEPS 256
#define NBLK   256
#define TPB    1024
#define WAVES  16
#define HROWS  16          // h rows per block
#define GROWS  48          // gate rows per block
#define RPW    3           // rows per wave (2 VGPR + 1 LDS)
#define NCH    8           // column chunks of 512

typedef _Float16 h2 __attribute__((ext_vector_type(2)));

__device__ __forceinline__ float fdot2f(uint32_t a, uint32_t b, float c) {
#if __has_builtin(__builtin_amdgcn_fdot2)
  return __builtin_amdgcn_fdot2(__builtin_bit_cast(h2, a),
                                __builtin_bit_cast(h2, b), c, false);
#else
  h2 x = __builtin_bit_cast(h2, a), y = __builtin_bit_cast(h2, b);
  return c + (float)x[0]*(float)y[0] + (float)x[1]*(float)y[1];
#endif
}
__device__ __forceinline__ uint32_t pkf16(float x, float y) {
  h2 v; v[0] = (_Float16)x; v[1] = (_Float16)y;
  return __builtin_bit_cast(uint32_t, v);
}
__device__ __forceinline__ uint4 cvt8(const float* p) {
  return make_uint4(pkf16(p[0],p[1]), pkf16(p[2],p[3]),
                    pkf16(p[4],p[5]), pkf16(p[6],p[7]));
}
__device__ __forceinline__ float dot4(float acc, uint4 a, uint4 b) {
  acc = fdot2f(a.x, b.x, acc); acc = fdot2f(a.y, b.y, acc);
  acc = fdot2f(a.z, b.z, acc); acc = fdot2f(a.w, b.w, acc);
  return acc;
}

__global__ __launch_bounds__(TPB, 4)
void lstm(const float* __restrict__ ctx, const float* __restrict__ u,
          const float* __restrict__ l1w, const float* __restrict__ l1b,
          const float* __restrict__ Wf,  const float* __restrict__ Wfb,
          const float* __restrict__ Wi,  const float* __restrict__ Wib,
          const float* __restrict__ Wc,  const float* __restrict__ Wcb,
          const float* __restrict__ Wow, const float* __restrict__ Wob,
          float* __restrict__ hf0, float* __restrict__ hf1,
          uint32_t* __restrict__ hh0, uint32_t* __restrict__ hh1,
          uint32_t* __restrict__ flags, float* __restrict__ out)
{
  __shared__ uint4 wlds[WAVES][HID/8];    // 1 LDS row per wave, 128 KB
  __shared__ uint4 zsh4[HID/8];           // z packed f16x2, 8 KB
  __shared__ float red[WAVES];
  __shared__ float pre[GROWS];
  __shared__ float cst[HROWS];
  __shared__ float bias[GROWS];
  __shared__ float wx[GROWS];             // column-4096 (x) weight per row
  __shared__ float x0sh;

  const int tid  = threadIdx.x;
  const int b    = blockIdx.x;
  const int wv   = tid >> 6;
  const int lane = tid & 63;

  uint32_t* z32 = (uint32_t*)zsh4;
  for (int i = tid; i < HID/2; i += TPB) z32[i] = 0u;
  if (tid < HROWS) cst[tid] = 0.f;
  if (tid < GROWS) {
    int g = tid / HROWS, j = tid % HROWS;
    const float* bw = (g==0 ? Wfb : (g==1 ? Wib : Wcb));
    const float* gw = (g==0 ? Wf  : (g==1 ? Wi  : Wc ));
    bias[tid] = bw[b*HROWS + j];
    wx[tid]   = gw[(size_t)(b*HROWS + j)*4097 + 4096];
  }

  // o-gate weights resident (step-invariant), f32
  float wow[4];
  #pragma unroll
  for (int k = 0; k < 4; ++k) wow[k] = Wow[tid + k*TPB];
  const float woxw = Wow[HID];
  const float wob0 = Wob[0];

  // load + convert this wave's 3 gate rows: 2 -> VGPRs, 1 -> LDS
  uint4 wrA[NCH], wrB[NCH];
  {
    const int fl0 = wv*RPW;
    const int g0 = (fl0+0)/HROWS, j0 = (fl0+0)%HROWS;
    const int g1 = (fl0+1)/HROWS, j1 = (fl0+1)%HROWS;
    const int g2 = (fl0+2)/HROWS, j2 = (fl0+2)%HROWS;
    const float* r0 = (g0==0?Wf:(g0==1?Wi:Wc)) + (size_t)(b*HROWS+j0)*4097;
    const float* r1 = (g1==0?Wf:(g1==1?Wi:Wc)) + (size_t)(b*HROWS+j1)*4097;
    const float* r2 = (g2==0?Wf:(g2==1?Wi:Wc)) + (size_t)(b*HROWS+j2)*4097;
    #pragma unroll
    for (int c = 0; c < NCH; ++c) {
      const int col = c*512 + lane*8;
      wrA[c] = cvt8(r0 + col);
      wrB[c] = cvt8(r1 + col);
      wlds[wv][c*64 + lane] = cvt8(r2 + col);
    }
  }

  // x0 = l1_w . context + l1_b (identical in every block); CTX == TPB
  {
    float p = l1w[tid] * ctx[tid];
    #pragma unroll
    for (int off = 32; off; off >>= 1) p += __shfl_down(p, off, 64);
    __syncthreads();                 // covers zsh4 zero-init + wlds + cst
    if (lane == 0) red[wv] = p;
    __syncthreads();
    if (tid == 0) {
      float ssum = 0.f;
      for (int w = 0; w < WAVES; ++w) ssum += red[w];
      x0sh = ssum + l1b[0];
    }
    __syncthreads();
  }
  float xcur = x0sh;
  float logp = 0.f;
  float hreg[4];
  #pragma unroll
  for (int k = 0; k < 4; ++k) hreg[k] = 0.f;

  for (int t = 0; t < NSTEPS; ++t) {
    // ---- o-gate partial (f32, identical in all blocks); reduce hides under dots
    float p = 0.f;
    #pragma unroll
    for (int k = 0; k < 4; ++k) p = fmaf(wow[k], hreg[k], p);
    #pragma unroll
    for (int off = 32; off; off >>= 1) p += __shfl_down(p, off, 64);
    if (lane == 0) red[wv] = p;
    __syncthreads();

    // ---- f/i/c gate dots from resident weights ----
    float a0 = 0.f, a1 = 0.f, a2 = 0.f;
    #pragma unroll
    for (int c = 0; c < NCH; ++c) {
      const uint4 zz = zsh4[c*64 + lane];
      const uint4 wl = wlds[wv][c*64 + lane];
      a0 = dot4(a0, wrA[c], zz);
      a1 = dot4(a1, wrB[c], zz);
      a2 = dot4(a2, wl, zz);
    }
    #pragma unroll
    for (int off = 32; off; off >>= 1) {
      a0 += __shfl_down(a0, off, 64);
      a1 += __shfl_down(a1, off, 64);
      a2 += __shfl_down(a2, off, 64);
    }

    // ---- finish o-gate (identical everywhere) ----
    float osum = 0.f;
    #pragma unroll
    for (int w = 0; w < WAVES; ++w) osum += red[w];
    const float opre = osum + woxw*xcur + wob0;
    const float o = 1.f / (1.f + expf(-opre));
    const float s = (u[t] < o) ? 1.f : 0.f;

    if (lane == 0) {
      const int fl = wv*RPW;
      pre[fl+0] = a0 + wx[fl+0]*xcur + bias[fl+0];
      pre[fl+1] = a1 + wx[fl+1]*xcur + bias[fl+1];
      pre[fl+2] = a2 + wx[fl+2]*xcur + bias[fl+2];
    }
    __syncthreads();

    // ---- h update: all stores from wave 0 so tid0's fence covers them ----
    float* hwF = (t & 1) ? hf1 : hf0;
    uint32_t* hwH = (t & 1) ? hh1 : hh0;
    float hv = 0.f;
    if (tid < HROWS) {
      const float ff = 1.f / (1.f + expf(-pre[tid]));
      const float ii = 1.f / (1.f + expf(-pre[HROWS+tid]));
      const float cc = tanhf(pre[2*HROWS+tid]);
      const float cn = ff*cst[tid] + ii*cc;
      cst[tid] = cn;
      hv = o * tanhf(cn);
      hwF[b*HROWS + tid] = hv;
    }
    if (tid < 64) {
      const float he = __shfl(hv, 2*(tid&7),   64);
      const float ho = __shfl(hv, 2*(tid&7)+1, 64);
      if (tid < 8) hwH[b*8 + tid] = pkf16(he, ho);
    }
    if (b == 0 && tid == 0) {
      logp += (s != 0.f) ? logf(o) : logf(1.f - o);
      out[t] = s;
    }
    xcur = s;

    if (t + 1 < NSTEPS) {
      // ---- flag barrier: release publish, relaxed poll, one acquire fence ----
      if (tid == 0) {
        __threadfence();
        __hip_atomic_store(&flags[b], (uint32_t)(t+1), __ATOMIC_RELEASE,
                           __HIP_MEMORY_SCOPE_AGENT);
      }
      if (tid < NBLK) {
        const uint32_t tg = (uint32_t)(t+1);
        while (__hip_atomic_load(&flags[tid], __ATOMIC_RELAXED,
                                 __HIP_MEMORY_SCOPE_AGENT) < tg)
          __builtin_amdgcn_s_sleep(1);
      }
      __syncthreads();
      __builtin_amdgcn_fence(__ATOMIC_ACQUIRE, "agent");

      // ---- gather z(t): f16 to LDS for gate dots, f32 to regs for o-gate ----
      const float*    hrF = (t & 1) ? hf1 : hf0;
      const uint32_t* hr2 = (t & 1) ? hh1 : hh0;
      #pragma unroll
      for (int k = 0; k < 4; ++k) hreg[k] = hrF[tid + k*TPB];
      #pragma unroll
      for (int k = 0; k < 2; ++k) z32[tid + k*TPB] = hr2[tid + k*TPB];
      __syncthreads();
    }
  }
  if (b == 0 && tid == 0) out[NSTEPS] = logp;
}

extern "C" void kernel_launch(void* const* d_in, const int* in_sizes, int n_in,
                              void* d_out, int out_size, void* d_ws, size_t ws_size,
                              hipStream_t stream) {
  const float* ctx = (const float*)d_in[0];
  const float* u   = (const float*)d_in[1];
  const float* l1w = (const float*)d_in[2];
  const float* l1b = (const float*)d_in[3];
  const float* Wf  = (const float*)d_in[4];
  const float* Wfb = (const float*)d_in[5];
  const float* Wi  = (const float*)d_in[6];
  const float* Wib = (const float*)d_in[7];
  const float* Wc  = (const float*)d_in[8];
  const float* Wcb = (const float*)d_in[9];
  const float* Wow = (const float*)d_in[10];
  const float* Wob = (const float*)d_in[11];
  float* out = (float*)d_out;

  char* ws = (char*)d_ws;
  uint32_t* flags = (uint32_t*)ws;                 // 256*4 B (memset 4 KB)
  float*    hf0   = (float*)(ws + 4096);
  float*    hf1   = (float*)(ws + 4096 + HID*4);
  uint32_t* hh0   = (uint32_t*)(ws + 4096 + 2*HID*4);
  uint32_t* hh1   = (uint32_t*)(ws + 4096 + 2*HID*4 + HID*2);

  (void)hipMemsetAsync(flags, 0, 4096, stream);
  lstm<<<NBLK, TPB, 0, stream>>>(ctx,u,l1w,l1b,Wf,Wfb,Wi,Wib,Wc,Wcb,Wow,Wob,
                                 hf0,hf1,hh0,hh1,flags,out);
}

// Round 6
// 11046.848 us; speedup vs baseline: 1.0026x; 1.0026x over previous
//
#include <hip/hip_runtime.h>
#include <hip/hip_fp16.h>
#include <stdint.h>

// LSTM policy rollout, weight-resident.
// 256 blocks x 1024 threads, 1 block/CU. amdgpu_waves_per_eu(4,4) pins the
// scheduler's occupancy target to exactly 4 waves/SIMD -> 128-VGPR budget,
// so the 64 weight VGPRs (2 rows f16x2 per wave) cannot be spilled.
// Block owns 16 h-rows = 48 gate rows; each of 16 waves: 2 rows VGPR + 1 LDS.
// Per-step global traffic = h exchange (24 KB/block) + 256 flag words.

#define HID    4096
#define CTX    1024
#define NSTEPS 256
#define NBLK   256
#define TPB    1024
#define WAVES  16
#define HROWS  16          // h rows per block
#define GROWS  48          // gate rows per block
#define RPW    3           // rows per wave (2 VGPR + 1 LDS)
#define NCH    8           // column chunks of 512

typedef _Float16 h2 __attribute__((ext_vector_type(2)));

__device__ __forceinline__ float fdot2f(uint32_t a, uint32_t b, float c) {
#if __has_builtin(__builtin_amdgcn_fdot2)
  return __builtin_amdgcn_fdot2(__builtin_bit_cast(h2, a),
                                __builtin_bit_cast(h2, b), c, false);
#else
  h2 x = __builtin_bit_cast(h2, a), y = __builtin_bit_cast(h2, b);
  return c + (float)x[0]*(float)y[0] + (float)x[1]*(float)y[1];
#endif
}
__device__ __forceinline__ uint32_t pkf16(float x, float y) {
  h2 v; v[0] = (_Float16)x; v[1] = (_Float16)y;
  return __builtin_bit_cast(uint32_t, v);
}
__device__ __forceinline__ uint4 cvt8(const float* p) {
  return make_uint4(pkf16(p[0],p[1]), pkf16(p[2],p[3]),
                    pkf16(p[4],p[5]), pkf16(p[6],p[7]));
}
__device__ __forceinline__ float dot4(float acc, uint4 a, uint4 b) {
  acc = fdot2f(a.x, b.x, acc); acc = fdot2f(a.y, b.y, acc);
  acc = fdot2f(a.z, b.z, acc); acc = fdot2f(a.w, b.w, acc);
  return acc;
}

__global__ __launch_bounds__(TPB)
__attribute__((amdgpu_waves_per_eu(4, 4)))
void lstm(const float* __restrict__ ctx, const float* __restrict__ u,
          const float* __restrict__ l1w, const float* __restrict__ l1b,
          const float* __restrict__ Wf,  const float* __restrict__ Wfb,
          const float* __restrict__ Wi,  const float* __restrict__ Wib,
          const float* __restrict__ Wc,  const float* __restrict__ Wcb,
          const float* __restrict__ Wow, const float* __restrict__ Wob,
          float* __restrict__ hf0, float* __restrict__ hf1,
          uint32_t* __restrict__ hh0, uint32_t* __restrict__ hh1,
          uint32_t* __restrict__ flags, float* __restrict__ out)
{
  __shared__ uint4 wlds[WAVES][HID/8];    // 1 LDS row per wave, 128 KB
  __shared__ uint4 zsh4[HID/8];           // z packed f16x2, 8 KB
  __shared__ float red[WAVES];
  __shared__ float pre[GROWS];
  __shared__ float cst[HROWS];
  __shared__ float bias[GROWS];
  __shared__ float wx[GROWS];             // column-4096 (x) weight per row
  __shared__ float x0sh;

  const int tid  = threadIdx.x;
  const int b    = blockIdx.x;
  const int wv   = tid >> 6;
  const int lane = tid & 63;

  uint32_t* z32 = (uint32_t*)zsh4;
  for (int i = tid; i < HID/2; i += TPB) z32[i] = 0u;
  if (tid < HROWS) cst[tid] = 0.f;
  if (tid < GROWS) {
    int g = tid / HROWS, j = tid % HROWS;
    const float* bw = (g==0 ? Wfb : (g==1 ? Wib : Wcb));
    const float* gw = (g==0 ? Wf  : (g==1 ? Wi  : Wc ));
    bias[tid] = bw[b*HROWS + j];
    wx[tid]   = gw[(size_t)(b*HROWS + j)*4097 + 4096];
  }

  // o-gate weights resident (step-invariant), f32
  float wow[4];
  #pragma unroll
  for (int k = 0; k < 4; ++k) wow[k] = Wow[tid + k*TPB];
  const float woxw = Wow[HID];
  const float wob0 = Wob[0];

  // load + convert this wave's 3 gate rows: 2 -> VGPRs, 1 -> LDS
  uint4 wrA[NCH], wrB[NCH];
  {
    const int fl0 = wv*RPW;
    const int g0 = (fl0+0)/HROWS, j0 = (fl0+0)%HROWS;
    const int g1 = (fl0+1)/HROWS, j1 = (fl0+1)%HROWS;
    const int g2 = (fl0+2)/HROWS, j2 = (fl0+2)%HROWS;
    const float* r0 = (g0==0?Wf:(g0==1?Wi:Wc)) + (size_t)(b*HROWS+j0)*4097;
    const float* r1 = (g1==0?Wf:(g1==1?Wi:Wc)) + (size_t)(b*HROWS+j1)*4097;
    const float* r2 = (g2==0?Wf:(g2==1?Wi:Wc)) + (size_t)(b*HROWS+j2)*4097;
    #pragma unroll
    for (int c = 0; c < NCH; ++c) {
      const int col = c*512 + lane*8;
      wrA[c] = cvt8(r0 + col);
      wrB[c] = cvt8(r1 + col);
      wlds[wv][c*64 + lane] = cvt8(r2 + col);
    }
  }

  // x0 = l1_w . context + l1_b (identical in every block); CTX == TPB
  {
    float p = l1w[tid] * ctx[tid];
    #pragma unroll
    for (int off = 32; off; off >>= 1) p += __shfl_down(p, off, 64);
    __syncthreads();                 // covers zsh4 zero-init + wlds + cst
    if (lane == 0) red[wv] = p;
    __syncthreads();
    if (tid == 0) {
      float ssum = 0.f;
      for (int w = 0; w < WAVES; ++w) ssum += red[w];
      x0sh = ssum + l1b[0];
    }
    __syncthreads();
  }
  float xcur = x0sh;
  float logp = 0.f;
  float hreg[4];
  #pragma unroll
  for (int k = 0; k < 4; ++k) hreg[k] = 0.f;

  for (int t = 0; t < NSTEPS; ++t) {
    // ---- o-gate partial (f32, identical in all blocks); reduce hides under dots
    float p = 0.f;
    #pragma unroll
    for (int k = 0; k < 4; ++k) p = fmaf(wow[k], hreg[k], p);
    #pragma unroll
    for (int off = 32; off; off >>= 1) p += __shfl_down(p, off, 64);
    if (lane == 0) red[wv] = p;
    __syncthreads();

    // ---- f/i/c gate dots from resident weights ----
    float a0 = 0.f, a1 = 0.f, a2 = 0.f;
    #pragma unroll
    for (int c = 0; c < NCH; ++c) {
      const uint4 zz = zsh4[c*64 + lane];
      const uint4 wl = wlds[wv][c*64 + lane];
      a0 = dot4(a0, wrA[c], zz);
      a1 = dot4(a1, wrB[c], zz);
      a2 = dot4(a2, wl, zz);
    }
    #pragma unroll
    for (int off = 32; off; off >>= 1) {
      a0 += __shfl_down(a0, off, 64);
      a1 += __shfl_down(a1, off, 64);
      a2 += __shfl_down(a2, off, 64);
    }

    // ---- finish o-gate (identical everywhere) ----
    float osum = 0.f;
    #pragma unroll
    for (int w = 0; w < WAVES; ++w) osum += red[w];
    const float opre = osum + woxw*xcur + wob0;
    const float o = 1.f / (1.f + expf(-opre));
    const float s = (u[t] < o) ? 1.f : 0.f;

    if (lane == 0) {
      const int fl = wv*RPW;
      pre[fl+0] = a0 + wx[fl+0]*xcur + bias[fl+0];
      pre[fl+1] = a1 + wx[fl+1]*xcur + bias[fl+1];
      pre[fl+2] = a2 + wx[fl+2]*xcur + bias[fl+2];
    }
    __syncthreads();

    // ---- h update: all stores from wave 0 so tid0's fence covers them ----
    float* hwF = (t & 1) ? hf1 : hf0;
    uint32_t* hwH = (t & 1) ? hh1 : hh0;
    float hv = 0.f;
    if (tid < HROWS) {
      const float ff = 1.f / (1.f + expf(-pre[tid]));
      const float ii = 1.f / (1.f + expf(-pre[HROWS+tid]));
      const float cc = tanhf(pre[2*HROWS+tid]);
      const float cn = ff*cst[tid] + ii*cc;
      cst[tid] = cn;
      hv = o * tanhf(cn);
      hwF[b*HROWS + tid] = hv;
    }
    if (tid < 64) {
      const float he = __shfl(hv, 2*(tid&7),   64);
      const float ho = __shfl(hv, 2*(tid&7)+1, 64);
      if (tid < 8) hwH[b*8 + tid] = pkf16(he, ho);
    }
    if (b == 0 && tid == 0) {
      logp += (s != 0.f) ? logf(o) : logf(1.f - o);
      out[t] = s;
    }
    xcur = s;

    if (t + 1 < NSTEPS) {
      // ---- flag barrier: release publish, relaxed poll, one acquire fence ----
      if (tid == 0) {
        __threadfence();
        __hip_atomic_store(&flags[b], (uint32_t)(t+1), __ATOMIC_RELEASE,
                           __HIP_MEMORY_SCOPE_AGENT);
      }
      if (tid < NBLK) {
        const uint32_t tg = (uint32_t)(t+1);
        while (__hip_atomic_load(&flags[tid], __ATOMIC_RELAXED,
                                 __HIP_MEMORY_SCOPE_AGENT) < tg)
          __builtin_amdgcn_s_sleep(1);
      }
      __syncthreads();
      __builtin_amdgcn_fence(__ATOMIC_ACQUIRE, "agent");

      // ---- gather z(t): f16 to LDS for gate dots, f32 to regs for o-gate ----
      const float*    hrF = (t & 1) ? hf1 : hf0;
      const uint32_t* hr2 = (t & 1) ? hh1 : hh0;
      #pragma unroll
      for (int k = 0; k < 4; ++k) hreg[k] = hrF[tid + k*TPB];
      #pragma unroll
      for (int k = 0; k < 2; ++k) z32[tid + k*TPB] = hr2[tid + k*TPB];
      __syncthreads();
    }
  }
  if (b == 0 && tid == 0) out[NSTEPS] = logp;
}

extern "C" void kernel_launch(void* const* d_in, const int* in_sizes, int n_in,
                              void* d_out, int out_size, void* d_ws, size_t ws_size,
                              hipStream_t stream) {
  const float* ctx = (const float*)d_in[0];
  const float* u   = (const float*)d_in[1];
  const float* l1w = (const float*)d_in[2];
  const float* l1b = (const float*)d_in[3];
  const float* Wf  = (const float*)d_in[4];
  const float* Wfb = (const float*)d_in[5];
  const float* Wi  = (const float*)d_in[6];
  const float* Wib = (const float*)d_in[7];
  const float* Wc  = (const float*)d_in[8];
  const float* Wcb = (const float*)d_in[9];
  const float* Wow = (const float*)d_in[10];
  const float* Wob = (const float*)d_in[11];
  float* out = (float*)d_out;

  char* ws = (char*)d_ws;
  uint32_t* flags = (uint32_t*)ws;                 // 256*4 B (memset 4 KB)
  float*    hf0   = (float*)(ws + 4096);
  float*    hf1   = (float*)(ws + 4096 + HID*4);
  uint32_t* hh0   = (uint32_t*)(ws + 4096 + 2*HID*4);
  uint32_t* hh1   = (uint32_t*)(ws + 4096 + 2*HID*4 + HID*2);

  (void)hipMemsetAsync(flags, 0, 4096, stream);
  lstm<<<NBLK, TPB, 0, stream>>>(ctx,u,l1w,l1b,Wf,Wfb,Wi,Wib,Wc,Wcb,Wow,Wob,
                                 hf0,hf1,hh0,hh1,flags,out);
}